// Round 7
// baseline (384.100 us; speedup 1.0000x reference)
//
#include <hip/hip_runtime.h>
#include <math.h>
#include <stdint.h>

// B=2, T=2048, E=1024, H=16, HS=64. bf16 MFMA.
// r7: gemm_big 256x128 (wave tile 64x128, 1 wave/SIMD, LDS/MFMA balanced)
// for QKV+FFN1; single lgkm-only barrier per K-iter everywhere (r6 had a
// redundant trailing barrier -- the dbuf ordering proof makes it safe).
typedef unsigned short u16;
typedef __attribute__((ext_vector_type(8))) short bf16x8;
typedef __attribute__((ext_vector_type(4))) float f32x4;

__device__ __forceinline__ u16 f2bf(float f) {
  unsigned int u = __float_as_uint(f);
  u += 0x7FFFu + ((u >> 16) & 1u);
  return (u16)(u >> 16);
}

// pack 2 floats -> 2 bf16 (round half-up) in one u32 via byte-perm
__device__ __forceinline__ unsigned pkbf(float a, float b) {
  unsigned ua = __float_as_uint(a) + 0x8000u;
  unsigned ub = __float_as_uint(b) + 0x8000u;
  return __builtin_amdgcn_perm(ub, ua, 0x07060302u);
}

// barrier that waits only LDS ops: global prefetch loads stay in flight.
__device__ __forceinline__ void lds_barrier() {
  asm volatile("s_waitcnt lgkmcnt(0)\n\ts_barrier" ::: "memory");
}

// ---------- tiled transpose fp32 [batch][R][C] -> bf16 [batch][C][R], ×scale ----------
__global__ __launch_bounds__(256) void transpose_bf16(
    const float* __restrict__ src, u16* __restrict__ dst,
    int R, int C, long sbs, long dbs, int drs, float scale) {
  __shared__ float tile[32][33];
  int c0 = blockIdx.x * 32, r0 = blockIdx.y * 32;
  long sb = (long)blockIdx.z * sbs, db = (long)blockIdx.z * dbs;
  int tx = threadIdx.x & 31, ty = threadIdx.x >> 5;
  #pragma unroll
  for (int k = 0; k < 4; ++k)
    tile[ty + k * 8][tx] = src[sb + (long)(r0 + ty + k * 8) * C + c0 + tx];
  __syncthreads();
  #pragma unroll
  for (int k = 0; k < 4; ++k)
    dst[db + (long)(c0 + ty + k * 8) * drs + r0 + tx] =
        f2bf(tile[tx][ty + k * 8] * scale);
}

// ---------- V^T builder: QKV V-cols -> VT [h][d=64][4096] bf16 ----------
__global__ __launch_bounds__(256) void vtrans(
    const u16* __restrict__ QKV, u16* __restrict__ VT) {
  __shared__ u16 Tl[64][72];
  int bt = blockIdx.x, h = blockIdx.y;
  int t = threadIdx.x;
  int r = t >> 3, c0 = (t & 7) << 3;
  const u16* src = QKV + (size_t)(bt * 64 + r) * 3072 + 2048 + h * 64 + c0;
  #pragma unroll
  for (int half = 0; half < 2; ++half) {
    bf16x8 v = *(const bf16x8*)(src + (size_t)(half * 32) * 3072);
    #pragma unroll
    for (int e = 0; e < 8; ++e) Tl[r + half * 32][c0 + e] = (u16)v[e];
  }
  __syncthreads();
  #pragma unroll
  for (int half = 0; half < 2; ++half) {
    int d = (t >> 3) + half * 32, s0 = (t & 7) << 3;
    bf16x8 o;
    #pragma unroll
    for (int e = 0; e < 8; ++e) o[e] = (short)Tl[s0 + e][d];
    *(bf16x8*)(VT + (size_t)(h * 64 + d) * 4096 + bt * 64 + s0) = o;
  }
}

// ---------- LayerNorm rows of 1024, bf16 out ----------
__global__ __launch_bounds__(256) void ln_bf16(
    const float* __restrict__ x, const float* __restrict__ g,
    const float* __restrict__ b, u16* __restrict__ out) {
  int row = blockIdx.x;
  const float* xr = x + (size_t)row * 1024;
  int t = threadIdx.x;
  float4 v = *(const float4*)(xr + t * 4);
  float s = v.x + v.y + v.z + v.w;
  float q = v.x * v.x + v.y * v.y + v.z * v.z + v.w * v.w;
  #pragma unroll
  for (int off = 32; off >= 1; off >>= 1) {
    s += __shfl_xor(s, off);
    q += __shfl_xor(q, off);
  }
  __shared__ float ss[4], qq[4];
  int wid = t >> 6;
  if ((t & 63) == 0) { ss[wid] = s; qq[wid] = q; }
  __syncthreads();
  float st = ss[0] + ss[1] + ss[2] + ss[3];
  float qt = qq[0] + qq[1] + qq[2] + qq[3];
  float mean = st * (1.0f / 1024.0f);
  float var = qt * (1.0f / 1024.0f) - mean * mean;
  float rstd = rsqrtf(var + 1e-5f);
  float4 gv = *(const float4*)(g + t * 4);
  float4 bv = *(const float4*)(b + t * 4);
  uint2 st2;
  st2.x = pkbf((v.x - mean) * rstd * gv.x + bv.x, (v.y - mean) * rstd * gv.y + bv.y);
  st2.y = pkbf((v.z - mean) * rstd * gv.z + bv.z, (v.w - mean) * rstd * gv.w + bv.w);
  *(uint2*)(out + (size_t)row * 1024 + t * 4) = st2;
}

// ---------- gemm_big: 256x128 block, wave tile 64x128, BK=64 ----------
// 4 waves (1/SIMD by design), dbuf LDS (96 KB), depth-1 prefetch, one
// lgkm barrier per iter. Requires M == 4096 (16 M-blocks for swizzle).
__global__ __launch_bounds__(256, 1) void gemm_big(
    const u16* __restrict__ A, const u16* __restrict__ Bt,
    const float* __restrict__ bias, float* __restrict__ Cf,
    u16* __restrict__ Cb, int N, int K, int relu) {
  __shared__ u16 As[2][256 * 64];
  __shared__ u16 Bs[2][128 * 64];
  int tid = threadIdx.x, wave = tid >> 6, lane = tid & 63;
  int lr = lane & 15, lq = lane >> 4;
  int lrow = lane >> 3, kblk = (lane & 7) ^ (lrow & 7);
  int g = blockIdx.x;
  int bm = ((((g & 7) << 1) | ((g >> 3) & 1))) * 256;
  int bn = (g >> 4) * 128;
  f32x4 acc[4][8];
  #pragma unroll
  for (int i = 0; i < 4; ++i)
    #pragma unroll
    for (int j = 0; j < 8; ++j) acc[i][j] = f32x4{0.f, 0.f, 0.f, 0.f};

  const u16* ag[8];
  #pragma unroll
  for (int j = 0; j < 8; ++j) {
    int c = wave * 8 + j;
    ag[j] = A + (size_t)(bm + c * 8 + lrow) * K + kblk * 8;
  }
  const u16* bg[4];
  #pragma unroll
  for (int j = 0; j < 4; ++j) {
    int c = wave * 4 + j;
    bg[j] = Bt + (size_t)(bn + c * 8 + lrow) * K + kblk * 8;
  }

  bf16x8 ra[8], rb[4];
  #pragma unroll
  for (int j = 0; j < 8; ++j) ra[j] = *(const bf16x8*)(ag[j]);
  #pragma unroll
  for (int j = 0; j < 4; ++j) rb[j] = *(const bf16x8*)(bg[j]);

  int nIter = K >> 6;
  for (int it = 0; it < nIter; ++it) {
    int buf = it & 1;
    #pragma unroll
    for (int j = 0; j < 8; ++j)
      *(bf16x8*)(&As[buf][(wave * 8 + j) * 512 + lane * 8]) = ra[j];
    #pragma unroll
    for (int j = 0; j < 4; ++j)
      *(bf16x8*)(&Bs[buf][(wave * 4 + j) * 512 + lane * 8]) = rb[j];
    lds_barrier();
    if (it + 1 < nIter) {
      int k0 = (it + 1) << 6;
      #pragma unroll
      for (int j = 0; j < 8; ++j) ra[j] = *(const bf16x8*)(ag[j] + k0);
      #pragma unroll
      for (int j = 0; j < 4; ++j) rb[j] = *(const bf16x8*)(bg[j] + k0);
    }
    #pragma unroll
    for (int kk = 0; kk < 2; ++kk) {
      bf16x8 af[4], bf[8];
      #pragma unroll
      for (int mi = 0; mi < 4; ++mi)
        af[mi] = *(const bf16x8*)(&As[buf][(wave * 64 + mi * 16 + lr) * 64 +
                                           (((kk << 2) + lq) ^ (lr & 7)) * 8]);
      #pragma unroll
      for (int ni = 0; ni < 8; ++ni)
        bf[ni] = *(const bf16x8*)(&Bs[buf][(ni * 16 + lr) * 64 +
                                           (((kk << 2) + lq) ^ (lr & 7)) * 8]);
      #pragma unroll
      for (int mi = 0; mi < 4; ++mi)
        #pragma unroll
        for (int ni = 0; ni < 8; ++ni)
          acc[mi][ni] = __builtin_amdgcn_mfma_f32_16x16x32_bf16(bf[ni], af[mi],
                                                                acc[mi][ni], 0, 0, 0);
    }
    // no trailing barrier: dbuf + next iter's top barrier order the reuse.
  }

  #pragma unroll
  for (int mi = 0; mi < 4; ++mi) {
    int row = bm + wave * 64 + mi * 16 + lr;
    #pragma unroll
    for (int ni = 0; ni < 8; ++ni) {
      int col = bn + ni * 16 + lq * 4;
      f32x4 v = acc[mi][ni];
      if (bias) {
        float4 bb = *(const float4*)(bias + col);
        v[0] += bb.x; v[1] += bb.y; v[2] += bb.z; v[3] += bb.w;
      }
      if (relu) {
        #pragma unroll
        for (int e = 0; e < 4; ++e) v[e] = fmaxf(v[e], 0.f);
      }
      if (Cb) {
        uint2 w;
        w.x = pkbf(v[0], v[1]);
        w.y = pkbf(v[2], v[3]);
        *(uint2*)(Cb + (size_t)row * N + col) = w;
      } else {
        float4 o;
        o.x = v[0]; o.y = v[1]; o.z = v[2]; o.w = v[3];
        *(float4*)(Cf + (size_t)row * N + col) = o;
      }
    }
  }
}

// ---------- pipelined bf16 MFMA GEMM (transposed acc): C = A[M,K] @ Bt[N,K]^T ----------
// BK=64, 256 threads (4 waves 2x2), dbuf LDS, depth-2 reg prefetch,
// ONE lgkm-only barrier per iter, XCD swizzle (assumes M/BM == 32).
template <int BM, int BN>
__global__ __launch_bounds__(256) void gemm_bf16(
    const u16* __restrict__ A, const u16* __restrict__ Bt,
    const float* __restrict__ bias, const float* __restrict__ res,
    float* __restrict__ Cf, u16* __restrict__ Cb,
    int M, int N, int K, int relu) {
  constexpr int MI = BM / 32, NI = BN / 32;
  constexpr int ACH = BM / 32, BCH = BN / 32;  // 1KB chunks per wave
  __shared__ u16 As[2][BM * 64];
  __shared__ u16 Bs[2][BN * 64];
  int tid = threadIdx.x, wave = tid >> 6, lane = tid & 63;
  int wm = wave >> 1, wn = wave & 1;
  int lr = lane & 15, lq = lane >> 4;
  int lrow = lane >> 3, kblk = (lane & 7) ^ (lrow & 7);
  int g = blockIdx.x;
  int bm = ((((g & 7) << 2) | ((g >> 3) & 3))) * BM;
  int bn = (g >> 5) * BN;
  f32x4 acc[MI][NI];
  #pragma unroll
  for (int i = 0; i < MI; ++i)
    #pragma unroll
    for (int j = 0; j < NI; ++j) acc[i][j] = f32x4{0.f, 0.f, 0.f, 0.f};

  const u16* ag[ACH];
  #pragma unroll
  for (int j = 0; j < ACH; ++j) {
    int c = wave * ACH + j;
    ag[j] = A + (size_t)(bm + c * 8 + lrow) * K + kblk * 8;
  }
  const u16* bg[BCH];
  #pragma unroll
  for (int j = 0; j < BCH; ++j) {
    int c = wave * BCH + j;
    bg[j] = Bt + (size_t)(bn + c * 8 + lrow) * K + kblk * 8;
  }

  bf16x8 ra0[ACH], ra1[ACH], rb0[BCH], rb1[BCH];
  #pragma unroll
  for (int j = 0; j < ACH; ++j) { ra0[j] = *(const bf16x8*)(ag[j]); ra1[j] = *(const bf16x8*)(ag[j] + 64); }
  #pragma unroll
  for (int j = 0; j < BCH; ++j) { rb0[j] = *(const bf16x8*)(bg[j]); rb1[j] = *(const bf16x8*)(bg[j] + 64); }

  int nIter = K >> 6;  // K is always a multiple of 128 here

#define GEMM_STEP(BUF, RA, RB, IT)                                                         \
  {                                                                                        \
    _Pragma("unroll") for (int j = 0; j < ACH; ++j)                                        \
        *(bf16x8*)(&As[BUF][(wave * ACH + j) * 512 + lane * 8]) = RA[j];                   \
    _Pragma("unroll") for (int j = 0; j < BCH; ++j)                                        \
        *(bf16x8*)(&Bs[BUF][(wave * BCH + j) * 512 + lane * 8]) = RB[j];                   \
    lds_barrier();                                                                         \
    if ((IT) + 2 < nIter) {                                                                \
      int k0 = ((IT) + 2) << 6;                                                            \
      _Pragma("unroll") for (int j = 0; j < ACH; ++j) RA[j] = *(const bf16x8*)(ag[j] + k0); \
      _Pragma("unroll") for (int j = 0; j < BCH; ++j) RB[j] = *(const bf16x8*)(bg[j] + k0); \
    }                                                                                      \
    _Pragma("unroll") for (int kk = 0; kk < 2; ++kk) {                                     \
      bf16x8 af[MI], bfr[NI];                                                              \
      _Pragma("unroll") for (int mi = 0; mi < MI; ++mi)                                    \
          af[mi] = *(const bf16x8*)(&As[BUF][(wm * (BM / 2) + mi * 16 + lr) * 64 +         \
                                             (((kk << 2) + lq) ^ (lr & 7)) * 8]);          \
      _Pragma("unroll") for (int ni = 0; ni < NI; ++ni)                                    \
          bfr[ni] = *(const bf16x8*)(&Bs[BUF][(wn * (BN / 2) + ni * 16 + lr) * 64 +        \
                                              (((kk << 2) + lq) ^ (lr & 7)) * 8]);         \
      _Pragma("unroll") for (int mi = 0; mi < MI; ++mi)                                    \
          _Pragma("unroll") for (int ni = 0; ni < NI; ++ni)                                \
              acc[mi][ni] = __builtin_amdgcn_mfma_f32_16x16x32_bf16(bfr[ni], af[mi],       \
                                                                    acc[mi][ni], 0, 0, 0); \
    }                                                                                      \
  }

  for (int it = 0; it < nIter; it += 2) {
    GEMM_STEP(0, ra0, rb0, it)
    GEMM_STEP(1, ra1, rb1, it + 1)
  }
#undef GEMM_STEP

  #pragma unroll
  for (int mi = 0; mi < MI; ++mi) {
    int row = bm + wm * (BM / 2) + mi * 16 + lr;
    #pragma unroll
    for (int ni = 0; ni < NI; ++ni) {
      int col = bn + wn * (BN / 2) + ni * 16 + lq * 4;
      f32x4 v = acc[mi][ni];
      if (bias) {
        float4 bb = *(const float4*)(bias + col);
        v[0] += bb.x; v[1] += bb.y; v[2] += bb.z; v[3] += bb.w;
      }
      if (res) {
        float4 rv = *(const float4*)(res + (size_t)row * N + col);
        v[0] += rv.x; v[1] += rv.y; v[2] += rv.z; v[3] += rv.w;
      }
      if (relu) {
        #pragma unroll
        for (int e = 0; e < 4; ++e) v[e] = fmaxf(v[e], 0.f);
      }
      if (Cb) {
        uint2 w;
        w.x = pkbf(v[0], v[1]);
        w.y = pkbf(v[2], v[3]);
        *(uint2*)(Cb + (size_t)row * N + col) = w;
      } else {
        float4 o;
        o.x = v[0]; o.y = v[1]; o.z = v[2]; o.w = v[3];
        *(float4*)(Cf + (size_t)row * N + col) = o;
      }
    }
  }
}

// ---------- MFMA flash attention: transposed (S^T/O^T), paired Q-tiles ----------
// QKV bf16 [4096][3072] (Q pre-scaled by 0.125*log2e); VT bf16 [16][64][4096].
// Block handles Q-tiles qtA=i and qtB=31-i (constant 33 tiles of work).
__global__ __launch_bounds__(256) void attn_mfma(
    const u16* __restrict__ QKV, const u16* __restrict__ VT,
    u16* __restrict__ O) {
  __shared__ u16 Klds[2][64 * 64];
  __shared__ u16 Vl[2][64 * 64];
  __shared__ u16 Pl[4][16 * 72];
  int i = blockIdx.x;  // 0..15
  int qtA = i, qtB = 31 - i;
  int b = blockIdx.y >> 4, hh = blockIdx.y & 15;
  int tid = threadIdx.x, wave = tid >> 6, lane = tid & 63;
  int lr = lane & 15, lq = lane >> 4;
  int lrow = lane >> 3, kb = (lane & 7) ^ (lrow & 7);

  const u16* qbase = QKV + (size_t)(b * 2048) * 3072 + hh * 64 + lq * 8;
  int qrA = qtA * 64 + wave * 16 + lr, qrB = qtB * 64 + wave * 16 + lr;
  bf16x8 qA0 = *(const bf16x8*)(qbase + (size_t)qrA * 3072);
  bf16x8 qA1 = *(const bf16x8*)(qbase + (size_t)qrA * 3072 + 32);
  bf16x8 qB0 = *(const bf16x8*)(qbase + (size_t)qrB * 3072);
  bf16x8 qB1 = *(const bf16x8*)(qbase + (size_t)qrB * 3072 + 32);

  f32x4 ofA[4], ofB[4];
  float lA = 0.f, lB = 0.f;
  #pragma unroll
  for (int d = 0; d < 4; ++d) {
    ofA[d] = f32x4{0.f, 0.f, 0.f, 0.f};
    ofB[d] = f32x4{0.f, 0.f, 0.f, 0.f};
  }

  const u16* kg[2];
  const u16* vg[2];
  #pragma unroll
  for (int j = 0; j < 2; ++j) {
    int c = wave * 2 + j;
    kg[j] = QKV + (size_t)(b * 2048 + c * 8 + lrow) * 3072 + 1024 + hh * 64 + kb * 8;
    vg[j] = VT + (size_t)(hh * 64 + c * 8 + lrow) * 4096 + b * 2048 + kb * 8;
  }
  bf16x8 rk[2], rv[2];
  #pragma unroll
  for (int j = 0; j < 2; ++j) {
    rk[j] = *(const bf16x8*)(kg[j]);
    rv[j] = *(const bf16x8*)(vg[j]);
  }

#define ATTN_TILE(Q0, Q1, QT, OF, LSUM)                                                    \
  {                                                                                        \
    f32x4 sf[4];                                                                           \
    _Pragma("unroll") for (int ni = 0; ni < 4; ++ni) sf[ni] = f32x4{0.f, 0.f, 0.f, 0.f};   \
    _Pragma("unroll") for (int ni = 0; ni < 4; ++ni) {                                     \
      int rowk = ni * 16 + lr;                                                             \
      bf16x8 k0 = *(const bf16x8*)(&Klds[buf][rowk * 64 + ((lq) ^ (lr & 7)) * 8]);         \
      bf16x8 k1 = *(const bf16x8*)(&Klds[buf][rowk * 64 + ((4 + lq) ^ (lr & 7)) * 8]);     \
      sf[ni] = __builtin_amdgcn_mfma_f32_16x16x32_bf16(k0, Q0, sf[ni], 0, 0, 0);           \
      sf[ni] = __builtin_amdgcn_mfma_f32_16x16x32_bf16(k1, Q1, sf[ni], 0, 0, 0);           \
    }                                                                                      \
    if (kt == (QT)) {                                                                      \
      _Pragma("unroll") for (int ni = 0; ni < 4; ++ni)                                     \
          _Pragma("unroll") for (int r = 0; r < 4; ++r)                                    \
              if (ni * 16 + lq * 4 + r > wave * 16 + lr) sf[ni][r] = -1e30f;               \
    }                                                                                      \
    _Pragma("unroll") for (int ni = 0; ni < 4; ++ni) {                                     \
      float p0 = exp2f(sf[ni][0]), p1 = exp2f(sf[ni][1]);                                  \
      float p2 = exp2f(sf[ni][2]), p3 = exp2f(sf[ni][3]);                                  \
      LSUM += (p0 + p1) + (p2 + p3);                                                       \
      uint2 w;                                                                             \
      w.x = pkbf(p0, p1);                                                                  \
      w.y = pkbf(p2, p3);                                                                  \
      *(uint2*)(&Pl[wave][lr * 72 + ni * 16 + lq * 4]) = w;                                \
    }                                                                                      \
    bf16x8 pf0 = *(const bf16x8*)(&Pl[wave][lr * 72 + lq * 8]);                            \
    bf16x8 pf1 = *(const bf16x8*)(&Pl[wave][lr * 72 + 32 + lq * 8]);                       \
    _Pragma("unroll") for (int di = 0; di < 4; ++di) {                                     \
      int rowv = di * 16 + lr;                                                             \
      bf16x8 v0 = *(const bf16x8*)(&Vl[buf][rowv * 64 + ((lq) ^ (lr & 7)) * 8]);           \
      bf16x8 v1 = *(const bf16x8*)(&Vl[buf][rowv * 64 + ((4 + lq) ^ (lr & 7)) * 8]);       \
      OF[di] = __builtin_amdgcn_mfma_f32_16x16x32_bf16(v0, pf0, OF[di], 0, 0, 0);          \
      OF[di] = __builtin_amdgcn_mfma_f32_16x16x32_bf16(v1, pf1, OF[di], 0, 0, 0);          \
    }                                                                                      \
  }

  for (int kt = 0; kt <= qtB; ++kt) {
    int buf = kt & 1;
    #pragma unroll
    for (int j = 0; j < 2; ++j) {
      *(bf16x8*)(&Klds[buf][(wave * 2 + j) * 512 + lane * 8]) = rk[j];
      *(bf16x8*)(&Vl[buf][(wave * 2 + j) * 512 + lane * 8]) = rv[j];
    }
    lds_barrier();
    if (kt < qtB) {
      #pragma unroll
      for (int j = 0; j < 2; ++j) {
        rk[j] = *(const bf16x8*)(kg[j] + (size_t)(kt + 1) * 64 * 3072);
        rv[j] = *(const bf16x8*)(vg[j] + (kt + 1) * 64);
      }
    }
    ATTN_TILE(qB0, qB1, qtB, ofB, lB)
    if (kt <= qtA) ATTN_TILE(qA0, qA1, qtA, ofA, lA)
    // no trailing barrier: dbuf ordering (see gemm) makes it redundant.
  }
#undef ATTN_TILE

  lB += __shfl_xor(lB, 16);
  lB += __shfl_xor(lB, 32);
  lA += __shfl_xor(lA, 16);
  lA += __shfl_xor(lA, 32);
  float invB = 1.0f / lB, invA = 1.0f / lA;
  u16* opB = O + (size_t)(b * 2048 + qtB * 64 + wave * 16 + lr) * 1024 + hh * 64;
  u16* opA = O + (size_t)(b * 2048 + qtA * 64 + wave * 16 + lr) * 1024 + hh * 64;
  #pragma unroll
  for (int di = 0; di < 4; ++di) {
    uint2 wB, wA;
    wB.x = pkbf(ofB[di][0] * invB, ofB[di][1] * invB);
    wB.y = pkbf(ofB[di][2] * invB, ofB[di][3] * invB);
    wA.x = pkbf(ofA[di][0] * invA, ofA[di][1] * invA);
    wA.y = pkbf(ofA[di][2] * invA, ofA[di][3] * invA);
    *(uint2*)(opB + di * 16 + lq * 4) = wB;
    *(uint2*)(opA + di * 16 + lq * 4) = wA;
  }
}

extern "C" void kernel_launch(void* const* d_in, const int* in_sizes, int n_in,
                              void* d_out, int out_size, void* d_ws, size_t ws_size,
                              hipStream_t stream) {
  const float* x   = (const float*)d_in[0];
  const float* Wq  = (const float*)d_in[1];
  const float* Wk  = (const float*)d_in[2];
  const float* Wv  = (const float*)d_in[3];
  const float* Wp  = (const float*)d_in[4];
  const float* bp  = (const float*)d_in[5];
  const float* W1  = (const float*)d_in[6];
  const float* b1  = (const float*)d_in[7];
  const float* W2  = (const float*)d_in[8];
  const float* b2  = (const float*)d_in[9];
  const float* g1  = (const float*)d_in[10];
  const float* be1 = (const float*)d_in[11];
  const float* g2  = (const float*)d_in[12];
  const float* be2 = (const float*)d_in[13];
  float* out = (float*)d_out;

  u16* ws16   = (u16*)d_ws;
  u16* Wqkv_t = ws16;                      // 3,145,728
  u16* Wp_t   = Wqkv_t + 3145728;          // 1,048,576
  u16* W1_t   = Wp_t + 1048576;            // 4,194,304
  u16* W2_t   = W1_t + 4194304;            // 4,194,304
  u16* h      = W2_t + 4194304;            // 4,194,304 (LN1 out; reused for LN2)
  u16* QKV    = h + 4194304;               // 12,582,912
  u16* Obuf   = QKV + 12582912;            // 4,194,304
  u16* f      = QKV;                       // 16,777,216 (overlaps QKV+Obuf)
  float* x1   = (float*)(Obuf + 4194304);  // 4,194,304 floats
  u16* VT     = (u16*)(x1 + 4194304);      // 4,194,304

  const float qsc = 0.18033688f;  // 0.125 * log2(e), folded into Wq
  transpose_bf16<<<dim3(2, 32, 16), 256, 0, stream>>>(Wq, Wqkv_t, 1024, 64, 65536, 65536, 1024, qsc);
  transpose_bf16<<<dim3(2, 32, 16), 256, 0, stream>>>(Wk, Wqkv_t + 1048576, 1024, 64, 65536, 65536, 1024, 1.f);
  transpose_bf16<<<dim3(2, 32, 16), 256, 0, stream>>>(Wv, Wqkv_t + 2097152, 1024, 64, 65536, 65536, 1024, 1.f);
  transpose_bf16<<<dim3(32, 32, 1), 256, 0, stream>>>(Wp, Wp_t, 1024, 1024, 0, 0, 1024, 1.f);
  transpose_bf16<<<dim3(128, 32, 1), 256, 0, stream>>>(W1, W1_t, 1024, 4096, 0, 0, 1024, 1.f);
  transpose_bf16<<<dim3(32, 128, 1), 256, 0, stream>>>(W2, W2_t, 4096, 1024, 0, 0, 4096, 1.f);

  ln_bf16<<<4096, 256, 0, stream>>>(x, g1, be1, h);
  gemm_big<<<384, 256, 0, stream>>>(h, Wqkv_t, nullptr, nullptr, QKV, 3072, 1024, 0);
  vtrans<<<dim3(64, 16), 256, 0, stream>>>(QKV, VT);
  attn_mfma<<<dim3(16, 32), 256, 0, stream>>>(QKV, VT, Obuf);
  gemm_bf16<128, 128><<<256, 256, 0, stream>>>(Obuf, Wp_t, bp, x,
                                               x1, nullptr, 4096, 1024, 1024, 0);
  ln_bf16<<<4096, 256, 0, stream>>>(x1, g2, be2, h);
  gemm_big<<<512, 256, 0, stream>>>(h, W1_t, b1, nullptr, f, 4096, 1024, 1);
  gemm_bf16<128, 128><<<256, 256, 0, stream>>>(f, W2_t, b2, x1,
                                               out, nullptr, 4096, 1024, 4096, 0);
}